// Round 1
// baseline (59.675 us; speedup 1.0000x reference)
//
#include <hip/hip_runtime.h>

#define NG 256
#define HH 512
#define WW 512
#define HW (HH*WW)
#define TWO_PI_F 6.283185307179586f

static __device__ __forceinline__ float clampf(float x, float lo, float hi) {
    return fminf(fmaxf(x, lo), hi);
}

__global__ __launch_bounds__(256) void gabor_fwd(
    const float* __restrict__ grid_x, const float* __restrict__ grid_y,
    const float* __restrict__ u,      const float* __restrict__ v,
    const float* __restrict__ theta,  const float* __restrict__ rel_sigma,
    const float* __restrict__ rel_freq, const float* __restrict__ gamma,
    const float* __restrict__ psi,    const float* __restrict__ amplitude,
    float* __restrict__ out)
{
    // Per-gabor constants staged in LDS (computed once per block, f64->f32
    // correctly-rounded so we track the numpy f32 reference as closely as
    // possible; freq's division is done in f32 to mirror np's op order).
    __shared__ float4 cA[NG]; // uc, vc, cr, sr
    __shared__ float4 cB[NG]; // i2s, i2g, freq, -
    __shared__ float4 cC[NG]; // amp*cos(phase) for c=0,1,2
    __shared__ float4 cD[NG]; // amp*sin(phase) for c=0,1,2

    const int tid = threadIdx.x;
    {
        const int n = tid;  // blockDim.x == NG == 256
        const float uc = clampf(u[n], -1.f, 1.f);
        const float vc = clampf(v[n], -1.f, 1.f);
        const float th = clampf(theta[n], -2.f, 2.f) * TWO_PI_F;
        const float sg = clampf(rel_sigma[n], 1e-5f, 5.f);
        const float gm = clampf(gamma[n], 1e-5f, 5.f);
        const float cr = (float)::cos((double)th);
        const float sr = (float)::sin((double)th);
        const float i2s = 1.0f / (2.0f * sg * sg);
        const float i2g = 1.0f / (2.0f * gm * gm);
        const float E  = (float)::exp((double)rel_freq[n]);
        const float fq = TWO_PI_F / E;   // f32 division, mirrors np
        cA[n] = make_float4(uc, vc, cr, sr);
        cB[n] = make_float4(i2s, i2g, fq, 0.f);
        float ac[3], as[3];
        #pragma unroll
        for (int c = 0; c < 3; ++c) {
            const float ph = clampf(psi[n*3 + c], -1.f, 1.f) * TWO_PI_F;
            const float a  = clampf(amplitude[n*3 + c], 0.f, 1.f);
            ac[c] = a * (float)::cos((double)ph);
            as[c] = a * (float)::sin((double)ph);
        }
        cC[n] = make_float4(ac[0], ac[1], ac[2], 0.f);
        cD[n] = make_float4(as[0], as[1], as[2], 0.f);
    }
    __syncthreads();

    const int p = blockIdx.x * 256 + tid;
    const float gx = grid_x[p];
    const float gy = grid_y[p];
    float a0 = 0.f, a1 = 0.f, a2 = 0.f;

    for (int n = 0; n < NG; ++n) {
        const float4 k0 = cA[n];
        const float4 k1 = cB[n];
        const float dx = gx - k0.x;
        const float dy = gy - k0.y;
        float xr, yr;
        {
            // fma contraction OFF here: fx = freq*xr is phase-critical and
            // freq can be ~1e6; we must match the reference's f32 rounding.
            #pragma clang fp contract(off)
            xr = dx * k0.z + dy * k0.w;
            yr = dy * k0.z - dx * k0.w;
        }
        const float e = -(xr * xr * k1.x + yr * yr * k1.y);
        // Reference clips e to [-80,80] then exp(); for e < -30 the gaussian
        // is < 1e-13 -> contribution below 1e-10, far under the 1.5e-2
        // threshold. Skip the transcendentals entirely.
        if (e > -30.0f) {
            const float g = __expf(e);   // not phase-critical, ~1e-6 rel err ok
            float fx;
            {
                #pragma clang fp contract(off)
                fx = k1.z * xr;
            }
            float s, c;
            sincosf(fx, &s, &c);         // accurate (full range reduction)
            const float gc = g * c;
            const float gs = g * s;
            const float4 k2 = cC[n];
            const float4 k3 = cD[n];
            {
                #pragma clang fp contract(off)
                a0 += gc * k2.x - gs * k3.x;
                a1 += gc * k2.y - gs * k3.y;
                a2 += gc * k2.z - gs * k3.z;
            }
        }
    }

    out[p]          = clampf(a0, -1.f, 1.f);
    out[HW + p]     = clampf(a1, -1.f, 1.f);
    out[2*HW + p]   = clampf(a2, -1.f, 1.f);
}

extern "C" void kernel_launch(void* const* d_in, const int* in_sizes, int n_in,
                              void* d_out, int out_size, void* d_ws, size_t ws_size,
                              hipStream_t stream) {
    const float* grid_x    = (const float*)d_in[0];
    const float* grid_y    = (const float*)d_in[1];
    const float* u         = (const float*)d_in[2];
    const float* v         = (const float*)d_in[3];
    const float* theta     = (const float*)d_in[4];
    const float* rel_sigma = (const float*)d_in[5];
    const float* rel_freq  = (const float*)d_in[6];
    const float* gamma     = (const float*)d_in[7];
    const float* psi       = (const float*)d_in[8];
    const float* amplitude = (const float*)d_in[9];
    float* out = (float*)d_out;

    gabor_fwd<<<HW / 256, 256, 0, stream>>>(
        grid_x, grid_y, u, v, theta, rel_sigma, rel_freq, gamma,
        psi, amplitude, out);
}

// Round 2
// 48.940 us; speedup vs baseline: 1.2194x; 1.2194x over previous
//
#include <hip/hip_runtime.h>

#define NG 256
#define HH 512
#define WW 512
#define HW (HH*WW)
#define TWO_PI_F 6.283185307179586f

static __device__ __forceinline__ float clampf(float x, float lo, float hi) {
    return fminf(fmaxf(x, lo), hi);
}

// sin/cos of f32 x (radians, |x| up to ~3e7) matching the exact f32 input:
// reduce in f64 (r = x/2pi exact to ~1e-9 rev), take fractional revolution,
// feed hardware v_sin_f32/v_cos_f32 (ISA semantics: D = sin(S0 * 2pi)).
static __device__ __forceinline__ void fast_sincos(float x, float* s, float* c) {
    const double INV2PI = 0.15915494309189535;
    double r = (double)x * INV2PI;
    double n = rint(r);
    float rev = (float)(r - n);          // [-0.5, 0.5]
    *s = __builtin_amdgcn_sinf(rev);
    *c = __builtin_amdgcn_cosf(rev);
}

__global__ __launch_bounds__(256) void gabor_fwd(
    const float* __restrict__ grid_x, const float* __restrict__ grid_y,
    const float* __restrict__ u,      const float* __restrict__ v,
    const float* __restrict__ theta,  const float* __restrict__ rel_sigma,
    const float* __restrict__ rel_freq, const float* __restrict__ gamma,
    const float* __restrict__ psi,    const float* __restrict__ amplitude,
    float* __restrict__ out)
{
    __shared__ float4 cA[NG]; // uc, vc, cr, sr
    __shared__ float4 cB[NG]; // i2s, i2g, freq, -
    __shared__ float4 cC[NG]; // amp*cos(phase) c=0,1,2
    __shared__ float4 cD[NG]; // amp*sin(phase) c=0,1,2

    const int tid = threadIdx.x;
    {
        const int n = tid;  // blockDim.x == NG == 256
        const float uc = clampf(u[n], -1.f, 1.f);
        const float vc = clampf(v[n], -1.f, 1.f);
        const float th = clampf(theta[n], -2.f, 2.f) * TWO_PI_F;
        const float sg = clampf(rel_sigma[n], 1e-5f, 5.f);
        const float gm = clampf(gamma[n], 1e-5f, 5.f);
        const float cr = (float)::cos((double)th);
        const float sr = (float)::sin((double)th);
        const float i2s = 1.0f / (2.0f * sg * sg);
        const float i2g = 1.0f / (2.0f * gm * gm);
        const float E  = (float)::exp((double)rel_freq[n]);
        const float fq = TWO_PI_F / E;   // f32 division, mirrors np
        cA[n] = make_float4(uc, vc, cr, sr);
        cB[n] = make_float4(i2s, i2g, fq, 0.f);
        float ac[3], as[3];
        #pragma unroll
        for (int c = 0; c < 3; ++c) {
            const float ph = clampf(psi[n*3 + c], -1.f, 1.f) * TWO_PI_F;
            const float a  = clampf(amplitude[n*3 + c], 0.f, 1.f);
            ac[c] = a * (float)::cos((double)ph);
            as[c] = a * (float)::sin((double)ph);
        }
        cC[n] = make_float4(ac[0], ac[1], ac[2], 0.f);
        cD[n] = make_float4(as[0], as[1], as[2], 0.f);
    }
    __syncthreads();

    const int p = blockIdx.x * 256 + tid;
    const float gx = grid_x[p];
    const float gy = grid_y[p];
    float a0 = 0.f, a1 = 0.f, a2 = 0.f;

    for (int n = 0; n < NG; ++n) {
        const float4 k0 = cA[n];
        const float4 k1 = cB[n];
        const float dx = gx - k0.x;
        const float dy = gy - k0.y;
        float xr, yr;
        {
            // fma contraction OFF: fx = freq*xr is phase-critical (freq up to
            // ~2e7); must match the reference's f32 rounding of x_rot.
            #pragma clang fp contract(off)
            xr = dx * k0.z + dy * k0.w;
            yr = dy * k0.z - dx * k0.w;
        }
        const float e = -(xr * xr * k1.x + yr * yr * k1.y);
        // For e < -30, gaussian < 1e-13 -> contribution ~1e-13, skip.
        if (e > -30.0f) {
            const float g = __expf(e);   // not phase-critical
            float fx;
            {
                #pragma clang fp contract(off)
                fx = k1.z * xr;
            }
            float s, c;
            fast_sincos(fx, &s, &c);
            const float gc = g * c;
            const float gs = g * s;
            const float4 k2 = cC[n];
            const float4 k3 = cD[n];
            {
                #pragma clang fp contract(off)
                a0 += gc * k2.x - gs * k3.x;
                a1 += gc * k2.y - gs * k3.y;
                a2 += gc * k2.z - gs * k3.z;
            }
        }
    }

    out[p]          = clampf(a0, -1.f, 1.f);
    out[HW + p]     = clampf(a1, -1.f, 1.f);
    out[2*HW + p]   = clampf(a2, -1.f, 1.f);
}

extern "C" void kernel_launch(void* const* d_in, const int* in_sizes, int n_in,
                              void* d_out, int out_size, void* d_ws, size_t ws_size,
                              hipStream_t stream) {
    const float* grid_x    = (const float*)d_in[0];
    const float* grid_y    = (const float*)d_in[1];
    const float* u         = (const float*)d_in[2];
    const float* v         = (const float*)d_in[3];
    const float* theta     = (const float*)d_in[4];
    const float* rel_sigma = (const float*)d_in[5];
    const float* rel_freq  = (const float*)d_in[6];
    const float* gamma     = (const float*)d_in[7];
    const float* psi       = (const float*)d_in[8];
    const float* amplitude = (const float*)d_in[9];
    float* out = (float*)d_out;

    gabor_fwd<<<HW / 256, 256, 0, stream>>>(
        grid_x, grid_y, u, v, theta, rel_sigma, rel_freq, gamma,
        psi, amplitude, out);
}

// Round 3
// 43.522 us; speedup vs baseline: 1.3711x; 1.1245x over previous
//
#include <hip/hip_runtime.h>

#define NG 256
#define HW (512*512)
#define TWO_PI_F 6.283185307179586f
#define L2E 1.4426950408889634f

static __device__ __forceinline__ float clampf(float x, float lo, float hi) {
    return fminf(fmaxf(x, lo), hi);
}

// Per-gabor constants, computed once per gabor (f64 -> correctly-rounded f32).
static __device__ __forceinline__ void compute_consts(
    int n,
    const float* __restrict__ u, const float* __restrict__ v,
    const float* __restrict__ theta, const float* __restrict__ rel_sigma,
    const float* __restrict__ rel_freq, const float* __restrict__ gamma,
    const float* __restrict__ psi, const float* __restrict__ amplitude,
    float4& A, float4& B, float4& C, float4& D)
{
    const float uc = clampf(u[n], -1.f, 1.f);
    const float vc = clampf(v[n], -1.f, 1.f);
    const float th = clampf(theta[n], -2.f, 2.f) * TWO_PI_F;
    const float sg = clampf(rel_sigma[n], 1e-5f, 5.f);
    const float gm = clampf(gamma[n], 1e-5f, 5.f);
    const float cr = (float)::cos((double)th);
    const float sr = (float)::sin((double)th);
    const float i2s = 1.0f / (2.0f * sg * sg);
    const float i2g = 1.0f / (2.0f * gm * gm);
    const float E  = (float)::exp((double)rel_freq[n]);
    const float fq = TWO_PI_F / E;          // f32 division, mirrors np
    A = make_float4(uc, vc, cr, sr);
    // negation + log2(e) folded: e2 = xr^2*B.x + yr^2*B.y is already
    // -(...)*log2e, ready for exp2.
    B = make_float4(-(i2s * L2E), -(i2g * L2E), fq, 0.f);
    float ac[3], as[3];
    #pragma unroll
    for (int c = 0; c < 3; ++c) {
        const float ph = clampf(psi[n*3 + c], -1.f, 1.f) * TWO_PI_F;
        const float a  = clampf(amplitude[n*3 + c], 0.f, 1.f);
        ac[c] = a * (float)::cos((double)ph);
        as[c] = a * (float)::sin((double)ph);
    }
    C = make_float4(ac[0], ac[1], ac[2], 0.f);
    D = make_float4(as[0], as[1], as[2], 0.f);
}

// Hot loop over all gabors for one pixel. Constants come from LDS.
static __device__ __forceinline__ void gabor_accum(
    const float4* __restrict__ cA, const float4* __restrict__ cB,
    const float4* __restrict__ cC, const float4* __restrict__ cD,
    float gx, float gy, float& a0, float& a1, float& a2)
{
    for (int n = 0; n < NG; ++n) {
        const float4 k0 = cA[n];
        const float4 k1 = cB[n];
        const float dx = gx - k0.x;
        const float dy = gy - k0.y;
        float xr, yr;
        {
            // phase-critical: must match np's separate-round mul/add
            #pragma clang fp contract(off)
            xr = dx * k0.z + dy * k0.w;
            yr = dy * k0.z - dx * k0.w;
        }
        // e2 = -(xr^2*i2s + yr^2*i2g)*log2e  (sign/scale folded into k1)
        const float e2 = fmaf(yr * yr, k1.y, xr * xr * k1.x);
        // exp2(-20) = 9.5e-7; 256 skipped gabors contribute <= 2.4e-4.
        if (e2 > -20.0f) {
            const float g = __builtin_amdgcn_exp2f(e2);
            float fx;
            {
                #pragma clang fp contract(off)
                fx = k1.z * xr;              // phase-critical f32 rounding
            }
            // exact reduction of the *rounded* f32 fx: f64 is wide enough
            // (needs ~46 bits) to get frac(fx/2pi) to ~1e-9 rev.
            double r = (double)fx * 0.15915494309189535;
            float rev = (float)(r - rint(r));        // [-0.5, 0.5] revolutions
            float s = __builtin_amdgcn_sinf(rev);    // v_sin_f32: sin(2pi*x)
            float c = __builtin_amdgcn_cosf(rev);
            const float4 k2 = cC[n];
            const float4 k3 = cD[n];
            a0 = fmaf(g, fmaf(-s, k3.x, c * k2.x), a0);
            a1 = fmaf(g, fmaf(-s, k3.y, c * k2.y), a1);
            a2 = fmaf(g, fmaf(-s, k3.z, c * k2.z), a2);
        }
    }
}

__global__ __launch_bounds__(NG) void gabor_consts_kernel(
    const float* __restrict__ u, const float* __restrict__ v,
    const float* __restrict__ theta, const float* __restrict__ rel_sigma,
    const float* __restrict__ rel_freq, const float* __restrict__ gamma,
    const float* __restrict__ psi, const float* __restrict__ amplitude,
    float4* __restrict__ ws)
{
    const int n = threadIdx.x;
    float4 A, B, C, D;
    compute_consts(n, u, v, theta, rel_sigma, rel_freq, gamma, psi, amplitude,
                   A, B, C, D);
    ws[n] = A; ws[NG + n] = B; ws[2*NG + n] = C; ws[3*NG + n] = D;
}

__global__ __launch_bounds__(256) void gabor_fwd_ws(
    const float4* __restrict__ ws,
    const float* __restrict__ grid_x, const float* __restrict__ grid_y,
    float* __restrict__ out)
{
    __shared__ float4 cs[4 * NG];
    const int tid = threadIdx.x;
    cs[tid]        = ws[tid];
    cs[tid + NG]   = ws[tid + NG];
    cs[tid + 2*NG] = ws[tid + 2*NG];
    cs[tid + 3*NG] = ws[tid + 3*NG];
    __syncthreads();

    const int p = blockIdx.x * 256 + tid;
    const float gx = grid_x[p];
    const float gy = grid_y[p];
    float a0 = 0.f, a1 = 0.f, a2 = 0.f;
    gabor_accum(cs, cs + NG, cs + 2*NG, cs + 3*NG, gx, gy, a0, a1, a2);
    out[p]        = clampf(a0, -1.f, 1.f);
    out[HW + p]   = clampf(a1, -1.f, 1.f);
    out[2*HW + p] = clampf(a2, -1.f, 1.f);
}

// Fallback (ws too small): fused prologue version.
__global__ __launch_bounds__(256) void gabor_fwd_fused(
    const float* __restrict__ grid_x, const float* __restrict__ grid_y,
    const float* __restrict__ u, const float* __restrict__ v,
    const float* __restrict__ theta, const float* __restrict__ rel_sigma,
    const float* __restrict__ rel_freq, const float* __restrict__ gamma,
    const float* __restrict__ psi, const float* __restrict__ amplitude,
    float* __restrict__ out)
{
    __shared__ float4 cs[4 * NG];
    const int tid = threadIdx.x;
    {
        float4 A, B, C, D;
        compute_consts(tid, u, v, theta, rel_sigma, rel_freq, gamma, psi,
                       amplitude, A, B, C, D);
        cs[tid] = A; cs[tid + NG] = B; cs[tid + 2*NG] = C; cs[tid + 3*NG] = D;
    }
    __syncthreads();
    const int p = blockIdx.x * 256 + tid;
    const float gx = grid_x[p];
    const float gy = grid_y[p];
    float a0 = 0.f, a1 = 0.f, a2 = 0.f;
    gabor_accum(cs, cs + NG, cs + 2*NG, cs + 3*NG, gx, gy, a0, a1, a2);
    out[p]        = clampf(a0, -1.f, 1.f);
    out[HW + p]   = clampf(a1, -1.f, 1.f);
    out[2*HW + p] = clampf(a2, -1.f, 1.f);
}

extern "C" void kernel_launch(void* const* d_in, const int* in_sizes, int n_in,
                              void* d_out, int out_size, void* d_ws, size_t ws_size,
                              hipStream_t stream) {
    const float* grid_x    = (const float*)d_in[0];
    const float* grid_y    = (const float*)d_in[1];
    const float* u         = (const float*)d_in[2];
    const float* v         = (const float*)d_in[3];
    const float* theta     = (const float*)d_in[4];
    const float* rel_sigma = (const float*)d_in[5];
    const float* rel_freq  = (const float*)d_in[6];
    const float* gamma     = (const float*)d_in[7];
    const float* psi       = (const float*)d_in[8];
    const float* amplitude = (const float*)d_in[9];
    float* out = (float*)d_out;

    if (ws_size >= 4u * NG * sizeof(float4)) {
        float4* ws = (float4*)d_ws;
        gabor_consts_kernel<<<1, NG, 0, stream>>>(
            u, v, theta, rel_sigma, rel_freq, gamma, psi, amplitude, ws);
        gabor_fwd_ws<<<HW / 256, 256, 0, stream>>>(ws, grid_x, grid_y, out);
    } else {
        gabor_fwd_fused<<<HW / 256, 256, 0, stream>>>(
            grid_x, grid_y, u, v, theta, rel_sigma, rel_freq, gamma,
            psi, amplitude, out);
    }
}